// Round 3
// baseline (92.600 us; speedup 1.0000x reference)
//
#include <hip/hip_runtime.h>
#include <hip/hip_fp16.h>

#define HW_  (1024 * 1024)   // 2^20
#define R_   4               // output rows per block
#define RS_  (R_ + 4)        // staged rows [r0-2, r0+R+1]
#define CW_  512             // output cols per block
#define SW_  (CW_ + 12)      // staged cols [c0-2, c0+CW+9]

// Each si0 owns exactly one output l: pi = (2*si0) mod 9, m0 = pi*2^20 + si0 = 9l.
// Taps q=0..8 are at si0+q (same pi unless si0 >= 2^20-8), shifted by (di,dj)(pi).
// Node = tap q=5. Fast path: 9 consecutive LDS reads. Fallback (col0>=1016): exact
// global-memory path (taps may row-wrap out of tile / cross pi boundary).
__global__ __launch_bounds__(256, 6) void ploss3(
        const float* __restrict__ logits_,
        const float* __restrict__ image_,
        float* __restrict__ out, int nwg, float scale) {
    __shared__ __half2 st[RS_ * SW_];   // 16.8 KB: {img, sigmoid(logits)} fp16

    // bijective XCD-chunked swizzle (nwg % 8 == 0)
    int bid = blockIdx.x;
    int wg  = (bid & 7) * (nwg >> 3) + (bid >> 3);

    int c   = wg >> 9;                 // 512 blocks per class
    int rem = wg & 511;
    int r0  = (rem >> 1) * R_;
    int c0  = (rem & 1) * CW_;
    const float* __restrict__ img = image_  + (size_t)c * HW_;
    const float* __restrict__ lg  = logits_ + (size_t)c * HW_;
    int tid = threadIdx.x;

    // ---- stage RS_ x SW_ tile: fp16{img, sigmoid}, OOB = 0 ----
    for (int rr = 0; rr < RS_; ++rr) {
        int row = r0 - 2 + rr;
        bool rok = (unsigned)row < 1024u;
        const float* gi = img + ((size_t)row << 10);
        const float* gl = lg  + ((size_t)row << 10);
        for (int sc = tid; sc < SW_; sc += 256) {
            int col = c0 - 2 + sc;
            float iv = 0.0f, mv = 0.0f;
            if (rok && (unsigned)col < 1024u) {
                iv = gi[col];
                mv = 1.0f / (1.0f + __expf(-gl[col]));
            }
            st[rr * SW_ + sc] = __floats2half2_rn(iv, mv);
        }
    }
    __syncthreads();

    const float T = 0.21072103131565256f;   // -2*ln(0.9): exp(-.5|d|)>=.9 <=> |d|<=T
    float acc = 0.0f;
    unsigned pi = (unsigned)(2 * ((r0 << 10) + c0 + tid)) % 9u;

    #pragma unroll
    for (int k = 0; k < 2 * R_; ++k) {
        int col0 = c0 + tid + ((k & 1) << 8);
        int row0 = r0 + (k >> 1);
        float timg[9], tm[9];
        bool fb = (c0 != 0) && (col0 >= 1016);
        if (!fb) {
            int i  = (int)((pi * 171u) >> 9);      // pi/3
            int j  = (int)pi - 3 * i;
            int di = 2 * i - 2, dj = 2 * j - 2;
            int a0 = ((k >> 1) + 2 + di) * SW_ + (tid + ((k & 1) << 8) + 2 + dj);
            #pragma unroll
            for (int q = 0; q < 9; ++q) {
                float2 v = __half22float2(st[a0 + q]);
                timg[q] = v.x; tm[q] = v.y;
            }
        } else {
            int m0 = (int)pi * HW_ + (row0 << 10) + col0;   // = 9l
            #pragma unroll
            for (int q = 0; q < 9; ++q) {
                int m = m0 + q;
                int piq = m >> 20, siq = m & (HW_ - 1);
                int iq = (piq * 171) >> 9, jq = piq - 3 * iq;
                int rq = (siq >> 10) + 2 * iq - 2;
                int cq = (siq & 1023) + 2 * jq - 2;
                float iv = 0.0f, mv = 0.0f;
                if ((unsigned)rq < 1024u && (unsigned)cq < 1024u) {
                    int off = (rq << 10) | cq;
                    iv = img[off];
                    mv = 1.0f / (1.0f + __expf(-lg[off]));
                }
                timg[q] = iv; tm[q] = mv;
            }
        }
        float nimg = timg[5], nm = tm[5];
        float t1 = 2.0f * nm - 1.0f, t2 = 1.0f - nm;
        #pragma unroll
        for (int q = 0; q < 9; ++q) {
            if (q == 4) continue;
            float prob = fmaf(tm[q], t1, t2);     // e*n + (1-e)(1-n)
            float lp = __logf(prob);              // always compute, predicated use
            acc -= (fabsf(nimg - timg[q]) <= T) ? lp : 0.0f;
        }
        pi += (k & 1) ? 6u : 8u;                  // 2*dsi mod 9: dsi=256->8, 768->6
        if (pi >= 9u) pi -= 9u;
    }
    acc *= scale;

    // wave shuffle reduce -> LDS -> one atomicAdd per block
    #pragma unroll
    for (int o = 32; o > 0; o >>= 1) acc += __shfl_down(acc, o, 64);
    __shared__ float sm[4];
    int lane = tid & 63, wid = tid >> 6;
    if (lane == 0) sm[wid] = acc;
    __syncthreads();
    if (tid == 0) atomicAdd(out, sm[0] + sm[1] + sm[2] + sm[3]);
}

extern "C" void kernel_launch(void* const* d_in, const int* in_sizes, int n_in,
                              void* d_out, int out_size, void* d_ws, size_t ws_size,
                              hipStream_t stream) {
    const float* logits = (const float*)d_in[0];  // inputs (N,1,H,W) fp32
    const float* image  = (const float*)d_in[1];  // image  (N,1,H,W) fp32
    float* out = (float*)d_out;

    int nc  = in_sizes[0] / HW_;                          // 4
    int nwg = nc * (1024 / R_) * (1024 / CW_);            // 2048
    float scale = 1.0f / ((float)nc * (float)HW_);

    hipMemsetAsync(out, 0, sizeof(float), stream);
    ploss3<<<nwg, 256, 0, stream>>>(logits, image, out, nwg, scale);
}

// Round 4
// 49.616 us; speedup vs baseline: 1.8663x; 1.8663x over previous
//
#include <hip/hip_runtime.h>
#include <hip/hip_fp16.h>

#define HW_  (1024 * 1024)   // 2^20
#define R_   4               // output rows per block
#define RS_  (R_ + 4)        // staged rows [r0-2, r0+5]
#define CW_  512             // output cols per block
#define SW_  528             // staged cols, multiple of 16 => di*SW_ bank-neutral

// Each si0 owns exactly one output l: pi = (2*si0) mod 9, m0 = pi*2^20 + si0 = 9l.
// Taps q=0..8 sit at si0+q (same pi, same row unless col0>=1016); node = tap q=5.
// Fast path: 9 consecutive LDS reads, streamed (NO local arrays -> no scratch).
// Fallback (col0>=1016, right tiles only): exact per-tap predicated global path.
__global__ __launch_bounds__(256, 6) void ploss4(
        const float* __restrict__ logits_,
        const float* __restrict__ image_,
        float* __restrict__ out, int nwg, float scale) {
    __shared__ __half2 st[RS_ * SW_];   // 16.9 KB: {img, sigmoid(logits)} fp16

    // bijective XCD-chunked swizzle (nwg % 8 == 0)
    int bid = blockIdx.x;
    int wg  = (bid & 7) * (nwg >> 3) + (bid >> 3);

    int c   = wg >> 9;                 // 512 blocks per class
    int rem = wg & 511;
    int r0  = (rem >> 1) * R_;
    int c0  = (rem & 1) * CW_;
    const float* __restrict__ img = image_  + (size_t)c * HW_;
    const float* __restrict__ lg  = logits_ + (size_t)c * HW_;
    int tid = threadIdx.x;

    // ---- stage RS_ x SW_ tile: fp16 {img, sigmoid(logits)}, OOB = 0 ----
    for (int rr = 0; rr < RS_; ++rr) {
        int row = r0 - 2 + rr;
        bool rok = (unsigned)row < 1024u;
        const float* gi = img + ((size_t)row << 10);
        const float* gl = lg  + ((size_t)row << 10);
        for (int sc = tid; sc < SW_; sc += 256) {
            int col = c0 - 2 + sc;
            float iv = 0.0f, mv = 0.0f;
            if (rok && (unsigned)col < 1024u) {
                iv = gi[col];
                mv = 1.0f / (1.0f + __expf(-gl[col]));
            }
            st[rr * SW_ + sc] = __floats2half2_rn(iv, mv);
        }
    }
    __syncthreads();

    const float T = 0.21072103131565256f;   // -2*ln(0.9): exp(-.5|d|)>=.9 <=> |d|<=T
    float acc = 0.0f;
    unsigned pi = (unsigned)(2u * (unsigned)((r0 << 10) + c0 + tid)) % 9u;

    #pragma unroll
    for (int k = 0; k < 2 * R_; ++k) {
        int colk = tid + ((k & 1) << 8);       // col within tile: 0..511
        int col0 = c0 + colk;
        int rowk = k >> 1;
        int i  = (int)((pi * 171u) >> 9);      // pi/3
        int j  = (int)pi - 3 * i;
        int di = 2 * i - 2, dj = 2 * j - 2;
        if (col0 < 1016) {
            // ---- fast path: stream 9 consecutive LDS taps ----
            int a0 = (rowk + 2 + di) * SW_ + (colk + 2 + dj);
            float2 nv = __half22float2(st[a0 + 5]);      // node = tap q=5
            float t1 = 2.0f * nv.y - 1.0f, t2 = 1.0f - nv.y;
            #pragma unroll
            for (int q = 0; q < 9; ++q) {
                if (q == 4) continue;
                float2 e = __half22float2(st[a0 + q]);
                float prob = fmaf(e.y, t1, t2);          // e*n + (1-e)(1-n)
                acc -= (fabsf(nv.x - e.x) <= T) ? __logf(prob) : 0.0f;
            }
        } else {
            // ---- rare exact path: taps may row-wrap / cross pi boundary ----
            int m0 = (int)pi * HW_ + ((r0 + rowk) << 10) + col0;   // = 9l
            float nimg = 0.0f, nm = 0.0f;
            {
                int m = m0 + 5;
                int piq = m >> 20, siq = m & (HW_ - 1);
                int iq = (piq * 171) >> 9, jq = piq - 3 * iq;
                int rq = (siq >> 10) + 2 * iq - 2;
                int cq = (siq & 1023) + 2 * jq - 2;
                if ((unsigned)rq < 1024u && (unsigned)cq < 1024u) {
                    int off = (rq << 10) | cq;
                    nimg = img[off];
                    nm = 1.0f / (1.0f + __expf(-lg[off]));
                }
            }
            float t1 = 2.0f * nm - 1.0f, t2 = 1.0f - nm;
            #pragma unroll
            for (int q = 0; q < 9; ++q) {
                if (q == 4) continue;
                int m = m0 + q;
                int piq = m >> 20, siq = m & (HW_ - 1);
                int iq = (piq * 171) >> 9, jq = piq - 3 * iq;
                int rq = (siq >> 10) + 2 * iq - 2;
                int cq = (siq & 1023) + 2 * jq - 2;
                float eimg = 0.0f, em = 0.0f;
                if ((unsigned)rq < 1024u && (unsigned)cq < 1024u) {
                    int off = (rq << 10) | cq;
                    eimg = img[off];
                    em = 1.0f / (1.0f + __expf(-lg[off]));
                }
                float prob = fmaf(em, t1, t2);
                acc -= (fabsf(nimg - eimg) <= T) ? __logf(prob) : 0.0f;
            }
        }
        pi += (k & 1) ? 6u : 8u;               // +2*dsi mod 9 (dsi: 256 / 768)
        if (pi >= 9u) pi -= 9u;
    }
    acc *= scale;

    // wave shuffle reduce -> LDS -> one atomicAdd per block
    #pragma unroll
    for (int o = 32; o > 0; o >>= 1) acc += __shfl_down(acc, o, 64);
    __shared__ float sm[4];
    int lane = tid & 63, wid = tid >> 6;
    if (lane == 0) sm[wid] = acc;
    __syncthreads();
    if (tid == 0) atomicAdd(out, sm[0] + sm[1] + sm[2] + sm[3]);
}

extern "C" void kernel_launch(void* const* d_in, const int* in_sizes, int n_in,
                              void* d_out, int out_size, void* d_ws, size_t ws_size,
                              hipStream_t stream) {
    const float* logits = (const float*)d_in[0];  // inputs (N,1,H,W) fp32
    const float* image  = (const float*)d_in[1];  // image  (N,1,H,W) fp32
    float* out = (float*)d_out;

    int nc  = in_sizes[0] / HW_;                          // 4
    int nwg = nc * (1024 / R_) * (1024 / CW_);            // 2048
    float scale = 1.0f / ((float)nc * (float)HW_);

    hipMemsetAsync(out, 0, sizeof(float), stream);
    ploss4<<<nwg, 256, 0, stream>>>(logits, image, out, nwg, scale);
}

// Round 5
// 47.217 us; speedup vs baseline: 1.9612x; 1.0508x over previous
//
#include <hip/hip_runtime.h>
#include <hip/hip_fp16.h>

#define HW_  (1024 * 1024)   // 2^20
#define R_   4               // output rows per block
#define RS_  (R_ + 4)        // staged rows [r0-2, r0+5]
#define CW_  512             // output cols per block
#define SW_  528             // staged cols, multiple of 16 => di*SW_ bank-neutral

// Each si0 owns exactly one output l: pi = (2*si0) mod 9, m0 = pi*2^20 + si0 = 9l.
// Taps q=0..8 sit at si0+q (same pi, same row unless col0>=1016); node = tap q=5.
// Fast path: 9 named-register LDS taps (MLP), product-of-probs, ONE log per iter.
__global__ __launch_bounds__(256) void ploss5(
        const float* __restrict__ logits_,
        const float* __restrict__ image_,
        float* __restrict__ out, int nwg, float scale) {
    __shared__ __half2 st[RS_ * SW_];   // 16.9 KB: {img, sigmoid(logits)} fp16

    // bijective XCD-chunked swizzle (nwg % 8 == 0)
    int bid = blockIdx.x;
    int wg  = (bid & 7) * (nwg >> 3) + (bid >> 3);

    int c   = wg >> 9;                 // 512 blocks per class
    int rem = wg & 511;
    int r0  = (rem >> 1) * R_;
    int c0  = (rem & 1) * CW_;
    const float* __restrict__ img = image_  + (size_t)c * HW_;
    const float* __restrict__ lg  = logits_ + (size_t)c * HW_;
    int tid = threadIdx.x;

    // ---- stage RS_ x SW_ tile: fp16 {img, sigmoid(logits)}, OOB = 0 ----
    for (int rr = 0; rr < RS_; ++rr) {
        int row = r0 - 2 + rr;
        bool rok = (unsigned)row < 1024u;
        const float* gi = img + ((size_t)row << 10);
        const float* gl = lg  + ((size_t)row << 10);
        for (int sc = tid; sc < SW_; sc += 256) {
            int col = c0 - 2 + sc;
            float iv = 0.0f, mv = 0.0f;
            if (rok && (unsigned)col < 1024u) {
                iv = gi[col];
                mv = 1.0f / (1.0f + __expf(-gl[col]));
            }
            st[rr * SW_ + sc] = __floats2half2_rn(iv, mv);
        }
    }
    __syncthreads();

    const float T = 0.21072103131565256f;   // -2*ln(0.9): exp(-.5|d|)>=.9 <=> |d|<=T
    float acc = 0.0f;
    unsigned pi = (unsigned)(2u * (unsigned)((r0 << 10) + c0 + tid)) % 9u;

    #pragma unroll
    for (int k = 0; k < 2 * R_; ++k) {
        int colk = tid + ((k & 1) << 8);       // col within tile: 0..511
        int col0 = c0 + colk;
        int rowk = k >> 1;
        int i  = (int)((pi * 171u) >> 9);      // pi/3
        int j  = (int)pi - 3 * i;
        int di = 2 * i - 2, dj = 2 * j - 2;
        if (col0 < 1016) {
            // ---- fast path: 9 independent named-register LDS taps (MLP) ----
            int a0 = (rowk + 2 + di) * SW_ + (colk + 2 + dj);
            float2 t0 = __half22float2(st[a0 + 0]);
            float2 t1 = __half22float2(st[a0 + 1]);
            float2 t2 = __half22float2(st[a0 + 2]);
            float2 t3 = __half22float2(st[a0 + 3]);
            float2 t5 = __half22float2(st[a0 + 5]);   // node
            float2 t6 = __half22float2(st[a0 + 6]);
            float2 t7 = __half22float2(st[a0 + 7]);
            float2 t8 = __half22float2(st[a0 + 8]);
            float2 t4n = __half22float2(st[a0 + 4]);  // edge q=... wait: q=4 excluded
            float nimg = t5.x, nm = t5.y;
            float c1 = 2.0f * nm - 1.0f, c2 = 1.0f - nm;
            float p = 1.0f;
            p *= (fabsf(nimg - t0.x) <= T) ? fmaf(t0.y, c1, c2) : 1.0f;
            p *= (fabsf(nimg - t1.x) <= T) ? fmaf(t1.y, c1, c2) : 1.0f;
            p *= (fabsf(nimg - t2.x) <= T) ? fmaf(t2.y, c1, c2) : 1.0f;
            p *= (fabsf(nimg - t3.x) <= T) ? fmaf(t3.y, c1, c2) : 1.0f;
            p *= (fabsf(nimg - t5.x) <= T) ? fmaf(t5.y, c1, c2) : 1.0f;  // q=5 edge (self)
            p *= (fabsf(nimg - t6.x) <= T) ? fmaf(t6.y, c1, c2) : 1.0f;
            p *= (fabsf(nimg - t7.x) <= T) ? fmaf(t7.y, c1, c2) : 1.0f;
            p *= (fabsf(nimg - t8.x) <= T) ? fmaf(t8.y, c1, c2) : 1.0f;
            (void)t4n;  // q=4 (column s//2) excluded from edge set
            acc -= __logf(p);
        } else {
            // ---- rare exact path: taps may row-wrap / cross pi boundary ----
            int m0 = (int)pi * HW_ + ((r0 + rowk) << 10) + col0;   // = 9l
            float nimg = 0.0f, nm = 0.0f;
            {
                int m = m0 + 5;
                int piq = m >> 20, siq = m & (HW_ - 1);
                int iq = (piq * 171) >> 9, jq = piq - 3 * iq;
                int rq = (siq >> 10) + 2 * iq - 2;
                int cq = (siq & 1023) + 2 * jq - 2;
                if ((unsigned)rq < 1024u && (unsigned)cq < 1024u) {
                    int off = (rq << 10) | cq;
                    nimg = img[off];
                    nm = 1.0f / (1.0f + __expf(-lg[off]));
                }
            }
            float c1 = 2.0f * nm - 1.0f, c2 = 1.0f - nm;
            float p = 1.0f;
            #pragma unroll
            for (int q = 0; q < 9; ++q) {
                if (q == 4) continue;
                int m = m0 + q;
                int piq = m >> 20, siq = m & (HW_ - 1);
                int iq = (piq * 171) >> 9, jq = piq - 3 * iq;
                int rq = (siq >> 10) + 2 * iq - 2;
                int cq = (siq & 1023) + 2 * jq - 2;
                float eimg = 0.0f, em = 0.0f;
                if ((unsigned)rq < 1024u && (unsigned)cq < 1024u) {
                    int off = (rq << 10) | cq;
                    eimg = img[off];
                    em = 1.0f / (1.0f + __expf(-lg[off]));
                }
                p *= (fabsf(nimg - eimg) <= T) ? fmaf(em, c1, c2) : 1.0f;
            }
            acc -= __logf(p);
        }
        pi += (k & 1) ? 6u : 8u;               // +2*dsi mod 9 (dsi: 256 / 768)
        if (pi >= 9u) pi -= 9u;
    }
    acc *= scale;

    // wave shuffle reduce -> LDS -> one atomicAdd per block
    #pragma unroll
    for (int o = 32; o > 0; o >>= 1) acc += __shfl_down(acc, o, 64);
    __shared__ float sm[4];
    int lane = tid & 63, wid = tid >> 6;
    if (lane == 0) sm[wid] = acc;
    __syncthreads();
    if (tid == 0) atomicAdd(out, sm[0] + sm[1] + sm[2] + sm[3]);
}

extern "C" void kernel_launch(void* const* d_in, const int* in_sizes, int n_in,
                              void* d_out, int out_size, void* d_ws, size_t ws_size,
                              hipStream_t stream) {
    const float* logits = (const float*)d_in[0];  // inputs (N,1,H,W) fp32
    const float* image  = (const float*)d_in[1];  // image  (N,1,H,W) fp32
    float* out = (float*)d_out;

    int nc  = in_sizes[0] / HW_;                          // 4
    int nwg = nc * (1024 / R_) * (1024 / CW_);            // 2048
    float scale = 1.0f / ((float)nc * (float)HW_);

    hipMemsetAsync(out, 0, sizeof(float), stream);
    ploss5<<<nwg, 256, 0, stream>>>(logits, image, out, nwg, scale);
}

// Round 6
// 33.585 us; speedup vs baseline: 2.7572x; 1.4059x over previous
//
#include <hip/hip_runtime.h>
#include <hip/hip_fp16.h>

#define HW_  (1024 * 1024)   // 2^20
#define R_   4               // output rows per block
#define RS_  (R_ + 4)        // staged rows [r0-2, r0+5]
#define CW_  512             // output cols per block
#define SW_  528             // staged cols, multiple of 16 => di*SW_ bank-neutral

// Each si0 owns exactly one output l: pi = (2*si0) mod 9, m0 = pi*2^20 + si0 = 9l.
// Taps q=0..8 sit at si0+q (same pi, same row unless col0>=1016); node = tap q=5.
// Fast path: 9 named-register LDS taps (MLP), product-of-probs, ONE log per iter.
// Reduction: per-block partial -> d_ws (NO same-address atomics), second kernel sums.
__global__ __launch_bounds__(256) void ploss6(
        const float* __restrict__ logits_,
        const float* __restrict__ image_,
        float* __restrict__ part, int nwg, float scale) {
    __shared__ __half2 st[RS_ * SW_];   // 16.9 KB: {img, sigmoid(logits)} fp16

    // bijective XCD-chunked swizzle (nwg % 8 == 0)
    int bid = blockIdx.x;
    int wg  = (bid & 7) * (nwg >> 3) + (bid >> 3);

    int c   = wg >> 9;                 // 512 blocks per class
    int rem = wg & 511;
    int r0  = (rem >> 1) * R_;
    int c0  = (rem & 1) * CW_;
    const float* __restrict__ img = image_  + (size_t)c * HW_;
    const float* __restrict__ lg  = logits_ + (size_t)c * HW_;
    int tid = threadIdx.x;

    // ---- stage RS_ x SW_ tile: fp16 {img, sigmoid(logits)}, OOB = 0 ----
    for (int rr = 0; rr < RS_; ++rr) {
        int row = r0 - 2 + rr;
        bool rok = (unsigned)row < 1024u;
        const float* gi = img + ((size_t)row << 10);
        const float* gl = lg  + ((size_t)row << 10);
        for (int sc = tid; sc < SW_; sc += 256) {
            int col = c0 - 2 + sc;
            float iv = 0.0f, mv = 0.0f;
            if (rok && (unsigned)col < 1024u) {
                iv = gi[col];
                mv = 1.0f / (1.0f + __expf(-gl[col]));
            }
            st[rr * SW_ + sc] = __floats2half2_rn(iv, mv);
        }
    }
    __syncthreads();

    const float T = 0.21072103131565256f;   // -2*ln(0.9): exp(-.5|d|)>=.9 <=> |d|<=T
    float acc = 0.0f;
    unsigned pi = (unsigned)(2u * (unsigned)((r0 << 10) + c0 + tid)) % 9u;

    #pragma unroll
    for (int k = 0; k < 2 * R_; ++k) {
        int colk = tid + ((k & 1) << 8);       // col within tile: 0..511
        int col0 = c0 + colk;
        int rowk = k >> 1;
        int i  = (int)((pi * 171u) >> 9);      // pi/3
        int j  = (int)pi - 3 * i;
        int di = 2 * i - 2, dj = 2 * j - 2;
        if (col0 < 1016) {
            // ---- fast path: 9 independent named-register LDS taps (MLP) ----
            int a0 = (rowk + 2 + di) * SW_ + (colk + 2 + dj);
            float2 t0 = __half22float2(st[a0 + 0]);
            float2 t1 = __half22float2(st[a0 + 1]);
            float2 t2 = __half22float2(st[a0 + 2]);
            float2 t3 = __half22float2(st[a0 + 3]);
            float2 t5 = __half22float2(st[a0 + 5]);   // node
            float2 t6 = __half22float2(st[a0 + 6]);
            float2 t7 = __half22float2(st[a0 + 7]);
            float2 t8 = __half22float2(st[a0 + 8]);
            float nimg = t5.x, nm = t5.y;
            float c1 = 2.0f * nm - 1.0f, c2 = 1.0f - nm;
            float p = 1.0f;
            p *= (fabsf(nimg - t0.x) <= T) ? fmaf(t0.y, c1, c2) : 1.0f;
            p *= (fabsf(nimg - t1.x) <= T) ? fmaf(t1.y, c1, c2) : 1.0f;
            p *= (fabsf(nimg - t2.x) <= T) ? fmaf(t2.y, c1, c2) : 1.0f;
            p *= (fabsf(nimg - t3.x) <= T) ? fmaf(t3.y, c1, c2) : 1.0f;
            p *= fmaf(t5.y, c1, c2);                  // q=5 edge (self, |d|=0<=T always)
            p *= (fabsf(nimg - t6.x) <= T) ? fmaf(t6.y, c1, c2) : 1.0f;
            p *= (fabsf(nimg - t7.x) <= T) ? fmaf(t7.y, c1, c2) : 1.0f;
            p *= (fabsf(nimg - t8.x) <= T) ? fmaf(t8.y, c1, c2) : 1.0f;
            acc -= __logf(p);
        } else {
            // ---- rare exact path: taps may row-wrap / cross pi boundary ----
            int m0 = (int)pi * HW_ + ((r0 + rowk) << 10) + col0;   // = 9l
            float nimg = 0.0f, nm = 0.0f;
            {
                int m = m0 + 5;
                int piq = m >> 20, siq = m & (HW_ - 1);
                int iq = (piq * 171) >> 9, jq = piq - 3 * iq;
                int rq = (siq >> 10) + 2 * iq - 2;
                int cq = (siq & 1023) + 2 * jq - 2;
                if ((unsigned)rq < 1024u && (unsigned)cq < 1024u) {
                    int off = (rq << 10) | cq;
                    nimg = img[off];
                    nm = 1.0f / (1.0f + __expf(-lg[off]));
                }
            }
            float c1 = 2.0f * nm - 1.0f, c2 = 1.0f - nm;
            float p = 1.0f;
            #pragma unroll
            for (int q = 0; q < 9; ++q) {
                if (q == 4) continue;
                int m = m0 + q;
                int piq = m >> 20, siq = m & (HW_ - 1);
                int iq = (piq * 171) >> 9, jq = piq - 3 * iq;
                int rq = (siq >> 10) + 2 * iq - 2;
                int cq = (siq & 1023) + 2 * jq - 2;
                float eimg = 0.0f, em = 0.0f;
                if ((unsigned)rq < 1024u && (unsigned)cq < 1024u) {
                    int off = (rq << 10) | cq;
                    eimg = img[off];
                    em = 1.0f / (1.0f + __expf(-lg[off]));
                }
                p *= (fabsf(nimg - eimg) <= T) ? fmaf(em, c1, c2) : 1.0f;
            }
            acc -= __logf(p);
        }
        pi += (k & 1) ? 6u : 8u;               // +2*dsi mod 9 (dsi: 256 / 768)
        if (pi >= 9u) pi -= 9u;
    }
    acc *= scale;

    // wave shuffle reduce -> LDS -> ONE plain store per block (no atomics)
    #pragma unroll
    for (int o = 32; o > 0; o >>= 1) acc += __shfl_down(acc, o, 64);
    __shared__ float sm[4];
    int lane = tid & 63, wid = tid >> 6;
    if (lane == 0) sm[wid] = acc;
    __syncthreads();
    if (tid == 0) part[wg] = sm[0] + sm[1] + sm[2] + sm[3];
}

// single-block final reduce of nwg partials
__global__ __launch_bounds__(256) void preduce(
        const float* __restrict__ part, float* __restrict__ out, int n) {
    float acc = 0.0f;
    for (int i = threadIdx.x; i < n; i += 256) acc += part[i];
    #pragma unroll
    for (int o = 32; o > 0; o >>= 1) acc += __shfl_down(acc, o, 64);
    __shared__ float sm[4];
    int lane = threadIdx.x & 63, wid = threadIdx.x >> 6;
    if (lane == 0) sm[wid] = acc;
    __syncthreads();
    if (threadIdx.x == 0) out[0] = sm[0] + sm[1] + sm[2] + sm[3];
}

extern "C" void kernel_launch(void* const* d_in, const int* in_sizes, int n_in,
                              void* d_out, int out_size, void* d_ws, size_t ws_size,
                              hipStream_t stream) {
    const float* logits = (const float*)d_in[0];  // inputs (N,1,H,W) fp32
    const float* image  = (const float*)d_in[1];  // image  (N,1,H,W) fp32
    float* out  = (float*)d_out;
    float* part = (float*)d_ws;                   // nwg floats of scratch

    int nc  = in_sizes[0] / HW_;                          // 4
    int nwg = nc * (1024 / R_) * (1024 / CW_);            // 2048
    float scale = 1.0f / ((float)nc * (float)HW_);

    ploss6<<<nwg, 256, 0, stream>>>(logits, image, part, nwg, scale);
    preduce<<<1, 256, 0, stream>>>(part, out, nwg);
}

// Round 7
// 23.916 us; speedup vs baseline: 3.8720x; 1.4043x over previous
//
#include <hip/hip_runtime.h>
#include <hip/hip_fp16.h>

#define HW_  (1024 * 1024)   // 2^20
#define R_   4               // output rows per block
#define RS_  (R_ + 4)        // staged rows [r0-2, r0+5]
#define CW_  512             // output cols per block
#define SW_  528             // staged cols [c0-4, c0+524), mult of 16 (bank-neutral di)
#define SOFF (RS_ * SW_)     // 4224 half2: strip starts here
#define NG   (SOFF / 4)      // 1056 float4 staging groups

// Each si0 owns one output l: pi = (2*si0) mod 9, m0 = pi*2^20 + si0 = 9l.
// Taps q=0..8 at si0+q, node = tap q=5. Fast path: 9 LDS taps. Row-wrap taps
// (col0>=1016) come from an 8x12 LDS strip (next row, cols -2..9). Only the
// pi-crossing sites (row0==1023 && col0>=1016; 32 threads grid-wide) go global.
__global__ __launch_bounds__(256) void ploss7(
        const float* __restrict__ logits_,
        const float* __restrict__ image_,
        float* __restrict__ part, int nwg, float scale) {
    __shared__ __half2 st[SOFF + 96];   // 17.3 KB

    // bijective XCD-chunked swizzle (nwg % 8 == 0)
    int bid = blockIdx.x;
    int wg  = (bid & 7) * (nwg >> 3) + (bid >> 3);

    int c   = wg >> 9;                 // 512 blocks per class
    int rem = wg & 511;
    int r0  = (rem >> 1) * R_;
    int c0  = (rem & 1) * CW_;
    const float* __restrict__ img = image_  + (size_t)c * HW_;
    const float* __restrict__ lg  = logits_ + (size_t)c * HW_;
    int tid = threadIdx.x;

    // ---- stage main tile: float4 groups, no partial vectors by construction ----
    for (unsigned g = tid; g < NG; g += 256) {
        unsigned rr = g / 132u;            // 132 groups per row
        int gc  = (int)(g - rr * 132u);
        int row = r0 - 2 + (int)rr;
        int col4 = c0 - 4 + (gc << 2);
        float4 w;
        __half2* wh = reinterpret_cast<__half2*>(&w);
        if ((unsigned)row < 1024u && (unsigned)col4 < 1021u) {
            const float4 a = *reinterpret_cast<const float4*>(img + ((size_t)row << 10) + col4);
            const float4 b = *reinterpret_cast<const float4*>(lg  + ((size_t)row << 10) + col4);
            wh[0] = __floats2half2_rn(a.x, 1.0f / (1.0f + __expf(-b.x)));
            wh[1] = __floats2half2_rn(a.y, 1.0f / (1.0f + __expf(-b.y)));
            wh[2] = __floats2half2_rn(a.z, 1.0f / (1.0f + __expf(-b.z)));
            wh[3] = __floats2half2_rn(a.w, 1.0f / (1.0f + __expf(-b.w)));
        } else {
            w = make_float4(0.0f, 0.0f, 0.0f, 0.0f);
        }
        reinterpret_cast<float4*>(st)[g] = w;
    }
    // ---- strip (right tiles only): rows [r0-1, r0+6], cols [-2, 10) ----
    if (c0 != 0 && tid < 96) {
        unsigned rr = (unsigned)tid / 12u;
        int cc = tid - (int)rr * 12;
        int row = r0 - 1 + (int)rr, col = cc - 2;
        float iv = 0.0f, mv = 0.0f;
        if ((unsigned)row < 1024u && (unsigned)col < 1024u) {
            int off = (row << 10) | col;
            iv = img[off];
            mv = 1.0f / (1.0f + __expf(-lg[off]));
        }
        st[SOFF + tid] = __floats2half2_rn(iv, mv);
    }
    __syncthreads();

    const float T = 0.21072103131565256f;   // -2*ln(0.9): exp(-.5|d|)>=.9 <=> |d|<=T
    float acc = 0.0f;                       // in log2 units; scale carries ln2
    unsigned pi = (2u * (unsigned)((r0 << 10) + c0 + tid)) % 9u;

    #pragma unroll
    for (int k = 0; k < 2 * R_; ++k) {
        int colk = tid + ((k & 1) << 8);       // col within tile: 0..511
        int col0 = c0 + colk;
        int rowk = k >> 1;
        int i  = (int)((pi * 171u) >> 9);      // pi/3
        int j  = (int)pi - 3 * i;
        int di = 2 * i - 2, dj = 2 * j - 2;
        int a0 = (rowk + 2 + di) * SW_ + (colk + 4 + dj);
        if (col0 < 1016) {
            // ---- fast path: 9 named-register LDS taps ----
            float2 t0 = __half22float2(st[a0 + 0]);
            float2 t1 = __half22float2(st[a0 + 1]);
            float2 t2 = __half22float2(st[a0 + 2]);
            float2 t3 = __half22float2(st[a0 + 3]);
            float2 t5 = __half22float2(st[a0 + 5]);   // node
            float2 t6 = __half22float2(st[a0 + 6]);
            float2 t7 = __half22float2(st[a0 + 7]);
            float2 t8 = __half22float2(st[a0 + 8]);
            float nimg = t5.x;
            float c1 = 2.0f * t5.y - 1.0f, c2 = 1.0f - t5.y;
            float f0 = (fabsf(nimg - t0.x) <= T) ? fmaf(t0.y, c1, c2) : 1.0f;
            float f1 = (fabsf(nimg - t1.x) <= T) ? fmaf(t1.y, c1, c2) : 1.0f;
            float f2 = (fabsf(nimg - t2.x) <= T) ? fmaf(t2.y, c1, c2) : 1.0f;
            float f3 = (fabsf(nimg - t3.x) <= T) ? fmaf(t3.y, c1, c2) : 1.0f;
            float f4 = fmaf(t5.y, c1, c2);            // self-edge q=5, |d|=0
            float f5 = (fabsf(nimg - t6.x) <= T) ? fmaf(t6.y, c1, c2) : 1.0f;
            float f6 = (fabsf(nimg - t7.x) <= T) ? fmaf(t7.y, c1, c2) : 1.0f;
            float f7 = (fabsf(nimg - t8.x) <= T) ? fmaf(t8.y, c1, c2) : 1.0f;
            float p = ((f0 * f1) * (f2 * f3)) * ((f4 * f5) * (f6 * f7));
            acc -= __log2f(p);
        } else if (r0 + rowk < 1023) {
            // ---- row-wrap path: taps q>=qs from the LDS strip ----
            int qs = 1024 - col0;                               // 1..8
            int sbase = SOFF + (rowk + 2 + di) * 12 + (colk + dj - 510);
            #define RDW_(q) __half22float2(st[(((q) < qs) ? a0 : sbase) + (q)])
            float2 t0 = RDW_(0);
            float2 t1 = RDW_(1);
            float2 t2 = RDW_(2);
            float2 t3 = RDW_(3);
            float2 t5 = RDW_(5);
            float2 t6 = RDW_(6);
            float2 t7 = RDW_(7);
            float2 t8 = RDW_(8);
            #undef RDW_
            float nimg = t5.x;
            float c1 = 2.0f * t5.y - 1.0f, c2 = 1.0f - t5.y;
            float f0 = (fabsf(nimg - t0.x) <= T) ? fmaf(t0.y, c1, c2) : 1.0f;
            float f1 = (fabsf(nimg - t1.x) <= T) ? fmaf(t1.y, c1, c2) : 1.0f;
            float f2 = (fabsf(nimg - t2.x) <= T) ? fmaf(t2.y, c1, c2) : 1.0f;
            float f3 = (fabsf(nimg - t3.x) <= T) ? fmaf(t3.y, c1, c2) : 1.0f;
            float f4 = fmaf(t5.y, c1, c2);
            float f5 = (fabsf(nimg - t6.x) <= T) ? fmaf(t6.y, c1, c2) : 1.0f;
            float f6 = (fabsf(nimg - t7.x) <= T) ? fmaf(t7.y, c1, c2) : 1.0f;
            float f7 = (fabsf(nimg - t8.x) <= T) ? fmaf(t8.y, c1, c2) : 1.0f;
            float p = ((f0 * f1) * (f2 * f3)) * ((f4 * f5) * (f6 * f7));
            acc -= __log2f(p);
        } else {
            // ---- pi-crossing sites (si0 >= 2^20-8): exact global path ----
            int m0 = (int)pi * HW_ + ((r0 + rowk) << 10) + col0;   // = 9l
            float nimg = 0.0f, nm = 0.0f;
            {
                int m = m0 + 5;
                int piq = m >> 20, siq = m & (HW_ - 1);
                int iq = (piq * 171) >> 9, jq = piq - 3 * iq;
                int rq = (siq >> 10) + 2 * iq - 2;
                int cq = (siq & 1023) + 2 * jq - 2;
                if ((unsigned)rq < 1024u && (unsigned)cq < 1024u) {
                    int off = (rq << 10) | cq;
                    nimg = img[off];
                    nm = 1.0f / (1.0f + __expf(-lg[off]));
                }
            }
            float c1 = 2.0f * nm - 1.0f, c2 = 1.0f - nm;
            float p = 1.0f;
            #pragma unroll
            for (int q = 0; q < 9; ++q) {
                if (q == 4) continue;
                int m = m0 + q;
                int piq = m >> 20, siq = m & (HW_ - 1);
                int iq = (piq * 171) >> 9, jq = piq - 3 * iq;
                int rq = (siq >> 10) + 2 * iq - 2;
                int cq = (siq & 1023) + 2 * jq - 2;
                float eimg = 0.0f, em = 0.0f;
                if ((unsigned)rq < 1024u && (unsigned)cq < 1024u) {
                    int off = (rq << 10) | cq;
                    eimg = img[off];
                    em = 1.0f / (1.0f + __expf(-lg[off]));
                }
                p *= (fabsf(nimg - eimg) <= T) ? fmaf(em, c1, c2) : 1.0f;
            }
            acc -= __log2f(p);
        }
        pi += (k & 1) ? 6u : 8u;               // +2*dsi mod 9 (dsi: 256 / 768)
        if (pi >= 9u) pi -= 9u;
    }
    acc *= scale;                              // scale includes ln2

    // wave shuffle reduce -> LDS -> ONE plain store per block (no atomics)
    #pragma unroll
    for (int o = 32; o > 0; o >>= 1) acc += __shfl_down(acc, o, 64);
    __shared__ float sm[4];
    int lane = tid & 63, wid = tid >> 6;
    if (lane == 0) sm[wid] = acc;
    __syncthreads();
    if (tid == 0) part[wg] = sm[0] + sm[1] + sm[2] + sm[3];
}

// single-block final reduce of nwg partials
__global__ __launch_bounds__(256) void preduce(
        const float* __restrict__ part, float* __restrict__ out, int n) {
    float acc = 0.0f;
    for (int i = threadIdx.x; i < n; i += 256) acc += part[i];
    #pragma unroll
    for (int o = 32; o > 0; o >>= 1) acc += __shfl_down(acc, o, 64);
    __shared__ float sm[4];
    int lane = threadIdx.x & 63, wid = threadIdx.x >> 6;
    if (lane == 0) sm[wid] = acc;
    __syncthreads();
    if (threadIdx.x == 0) out[0] = sm[0] + sm[1] + sm[2] + sm[3];
}

extern "C" void kernel_launch(void* const* d_in, const int* in_sizes, int n_in,
                              void* d_out, int out_size, void* d_ws, size_t ws_size,
                              hipStream_t stream) {
    const float* logits = (const float*)d_in[0];  // inputs (N,1,H,W) fp32
    const float* image  = (const float*)d_in[1];  // image  (N,1,H,W) fp32
    float* out  = (float*)d_out;
    float* part = (float*)d_ws;                   // nwg floats of scratch

    int nc  = in_sizes[0] / HW_;                          // 4
    int nwg = nc * (1024 / R_) * (1024 / CW_);            // 2048
    // acc is in log2 units -> fold ln2 into the scale
    float scale = 0.69314718055994531f / ((float)nc * (float)HW_);

    ploss7<<<nwg, 256, 0, stream>>>(logits, image, part, nwg, scale);
    preduce<<<1, 256, 0, stream>>>(part, out, nwg);
}